// Round 11
// baseline (201.612 us; speedup 1.0000x reference)
//
#include <hip/hip_runtime.h>
#include <hip/hip_bf16.h>
#include <math.h>

#define C_CLS   1024
#define NPROXY  8
#define ALLNUM  8192
#define DIM     512
#define TOPK    410
#define LAM     0.3f
#define BATCH   2048

typedef __bf16 bf16x8 __attribute__((ext_vector_type(8)));
typedef float floatx4 __attribute__((ext_vector_type(4)));
typedef unsigned short ushort_t;

// ws layout (float offsets)
#define WS_RNORM 0                      // 8192
#define WS_SIG   8192                   // 2048
#define WS_LP    10240                  // 2048
#define WS_RP    12288                  // 2048
#define WS_ABF   14336                  // 2048*512 bf16 = 524288 float-slots
#define WS_PBF   538624                 // 8192*512 bf16 = 2097152
#define WS_STBF  2635776                // 1024*512 bf16 = 262144
#define WS_LOG   2897920                // 8192*1024 bf16 = 4194304 (NOT aliased w/ sim!)
#define WS_SIM   7092224                // 2048*8192 fp32 = 16777216

// ---------------- helpers ----------------------------------------------------
__device__ inline float block_reduce(float v, int is_max, float* red, int t) {
    #pragma unroll
    for (int o = 32; o > 0; o >>= 1) {
        float w = __shfl_down(v, o);
        v = is_max ? fmaxf(v, w) : (v + w);
    }
    __syncthreads();
    if ((t & 63) == 0) red[t >> 6] = v;
    __syncthreads();
    return is_max ? fmaxf(fmaxf(red[0], red[1]), fmaxf(red[2], red[3]))
                  : (red[0] + red[1] + red[2] + red[3]);
}

__device__ inline ushort_t f2bf(float f) {   // RNE float->bf16
    unsigned u = __float_as_uint(f);
    return (ushort_t)((u + 0x7FFFu + ((u >> 16) & 1u)) >> 16);
}

__device__ inline void ld_g2l_16(const void* g, void* l) {
    __builtin_amdgcn_global_load_lds(
        (const __attribute__((address_space(1))) unsigned int*)g,
        (__attribute__((address_space(3))) unsigned int*)l,
        16, 0, 0);
}

__device__ inline unsigned f2ord(float f) {  // monotone float->uint
    unsigned u = __float_as_uint(f);
    return (u & 0x80000000u) ? ~u : (u | 0x80000000u);
}

// ---------------- K1: colnorm(256 blk) | convA+rowsig(1024) | tconvP(4096) ---
__global__ __launch_bounds__(256) void k_prep1(const float* __restrict__ P,
                                               const float* __restrict__ input,
                                               float* __restrict__ rnorm,
                                               float* __restrict__ rowsig,
                                               ushort_t* __restrict__ Abf,
                                               ushort_t* __restrict__ Pbf) {
    __shared__ float tile[32][33];
    float* cred = &tile[0][0];
    int bx = blockIdx.x, t = threadIdx.x;
    if (bx < 256) {
        // colnorm: 32 cols/block, 8 d-groups of 64
        int tc = t & 31, g = t >> 5;
        int c = bx * 32 + tc;
        const float* pc = P + (size_t)(g * 64) * ALLNUM + c;
        float s = 0.f;
        #pragma unroll 8
        for (int d = 0; d < 64; ++d) {
            float v = pc[(size_t)d * ALLNUM];
            s += v * v;
        }
        cred[g * 32 + tc] = s;
        __syncthreads();
        if (g == 0) {
            float tot = 0.f;
            #pragma unroll
            for (int k = 0; k < 8; ++k) tot += cred[k * 32 + tc];
            rnorm[c] = 1.0f / fmaxf(sqrtf(tot), 1e-12f);
        }
    } else if (bx < 256 + 1024) {
        // convA: input fp32 -> bf16 + row norms (block = exactly 2 rows)
        int a = bx - 256;
        int idx = a * 256 + t;
        float4 v = ((const float4*)input)[idx];
        ushort4 o;
        o.x = f2bf(v.x); o.y = f2bf(v.y); o.z = f2bf(v.z); o.w = f2bf(v.w);
        ((ushort4*)Abf)[idx] = o;
        float sq = v.x * v.x + v.y * v.y + v.z * v.z + v.w * v.w;
        #pragma unroll
        for (int off = 32; off > 0; off >>= 1) sq += __shfl_down(sq, off);
        int lane = t & 63, w = t >> 6;
        if (lane == 0) cred[w] = sq;
        __syncthreads();
        if (t == 0) {
            rowsig[2 * a]     = sqrtf(cred[0] + cred[1]);
            rowsig[2 * a + 1] = sqrtf(cred[2] + cred[3]);
        }
    } else {
        // tconv: P [512][8192] fp32 -> Pbf [8192][512] bf16
        int id = bx - 1280;
        int c0 = (id & 255) * 32, r0 = (id >> 8) * 32;
        int tc = t & 31, tr = t >> 5;
        #pragma unroll
        for (int p = 0; p < 4; ++p)
            tile[tr + p * 8][tc] = P[(size_t)(r0 + tr + p * 8) * ALLNUM + c0 + tc];
        __syncthreads();
        #pragma unroll
        for (int p = 0; p < 4; ++p) {
            int oc = tr + p * 8;
            Pbf[(size_t)(c0 + oc) * DIM + r0 + tc] = f2bf(tile[tc][oc]);
        }
    }
}

// ---------------- K2: gemm0 (sim f32, 1024 blk) | buildSt (512 blk) ----------
__global__ __launch_bounds__(256) void k_stage2(const ushort_t* __restrict__ A,
                                                const ushort_t* __restrict__ B,
                                                const float* __restrict__ P,
                                                const float* __restrict__ rnorm,
                                                float* __restrict__ sim,
                                                ushort_t* __restrict__ Stbf) {
    __shared__ __align__(16) ushort_t smem[2 * 128 * 64];   // 32 KB
    int bx = blockIdx.x, t = threadIdx.x;

    if (bx < 1024) {
        // ---- gemm0: sim = A(2048x512) @ B(8192x512)^T, *rnorm[col], f32 out
        ushort_t* sA = smem;
        ushort_t* sB = smem + 128 * 64;
        int w = t >> 6, lane = t & 63;
        int wm = w >> 1, wn = w & 1;
        int bj = (bx & 63) * 128, bi = (bx >> 6) * 128;

        floatx4 acc[4][4];
        #pragma unroll
        for (int tm = 0; tm < 4; ++tm)
            #pragma unroll
            for (int tn = 0; tn < 4; ++tn)
                acc[tm][tn] = (floatx4){0.f, 0.f, 0.f, 0.f};

        for (int k0 = 0; k0 < DIM; k0 += 64) {
            #pragma unroll
            for (int it = 0; it < 4; ++it) {
                int c = w * 256 + it * 64 + lane;
                int m = c >> 3, s = c & 7;
                int q = s ^ (m & 7);
                ld_g2l_16(A + ((size_t)(bi + m) << 9) + k0 + q * 8,
                          &sA[(w * 256 + it * 64) * 8]);
            }
            #pragma unroll
            for (int it = 0; it < 4; ++it) {
                int c = w * 256 + it * 64 + lane;
                int m = c >> 3, s = c & 7;
                int q = s ^ (m & 7);
                ld_g2l_16(B + ((size_t)(bj + m) << 9) + k0 + q * 8,
                          &sB[(w * 256 + it * 64) * 8]);
            }
            asm volatile("s_waitcnt vmcnt(0)" ::: "memory");
            __syncthreads();

            #pragma unroll
            for (int kk = 0; kk < 2; ++kk) {
                bf16x8 af[4], bfr[4];
                int ml = lane & 15, q = lane >> 4;
                #pragma unroll
                for (int tm = 0; tm < 4; ++tm) {
                    int m = wm * 64 + tm * 16 + ml;
                    int s = (kk * 4 + q) ^ (m & 7);
                    af[tm] = *(const bf16x8*)&sA[m * 64 + s * 8];
                }
                #pragma unroll
                for (int tn = 0; tn < 4; ++tn) {
                    int n = wn * 64 + tn * 16 + ml;
                    int s = (kk * 4 + q) ^ (n & 7);
                    bfr[tn] = *(const bf16x8*)&sB[n * 64 + s * 8];
                }
                #pragma unroll
                for (int tm = 0; tm < 4; ++tm)
                    #pragma unroll
                    for (int tn = 0; tn < 4; ++tn)
                        acc[tm][tn] = __builtin_amdgcn_mfma_f32_16x16x32_bf16(
                            af[tm], bfr[tn], acc[tm][tn], 0, 0, 0);
            }
            __syncthreads();
        }

        int ml = lane & 15, qd = lane >> 4;
        #pragma unroll
        for (int tm = 0; tm < 4; ++tm) {
            int rowb = bi + wm * 64 + tm * 16 + qd * 4;
            #pragma unroll
            for (int tn = 0; tn < 4; ++tn) {
                int col = bj + wn * 64 + tn * 16 + ml;
                float sc = rnorm[col];
                #pragma unroll
                for (int i = 0; i < 4; ++i)
                    sim[(size_t)(rowb + i) * ALLNUM + col] = acc[tm][tn][i] * sc;
            }
        }
    } else {
        // ---- buildSt: St[c][d] = sum_n P[d][8c+n]*rnorm[8c+n], bf16 out
        // 512 blocks: 32 c-tiles x 16 d-tiles (d0 < 512!)
        float* tile = (float*)smem;          // [32][33]
        int id = bx - 1024;                  // 0..511
        int c0 = (id & 31) * 32, d0 = (id >> 5) * 32;
        int cl = t & 31, dl8 = t >> 5;
        #pragma unroll
        for (int p = 0; p < 4; ++p) {
            int d = d0 + dl8 + 8 * p;
            int c = c0 + cl;
            const float* pp = P + (size_t)d * ALLNUM + c * NPROXY;
            const float* rn = rnorm + c * NPROXY;
            float4 a = *(const float4*)pp;
            float4 b = *(const float4*)(pp + 4);
            float4 ra = *(const float4*)rn;
            float4 rb = *(const float4*)(rn + 4);
            tile[(dl8 + 8 * p) * 33 + cl] =
                a.x * ra.x + a.y * ra.y + a.z * ra.z + a.w * ra.w +
                b.x * rb.x + b.y * rb.y + b.z * rb.z + b.w * rb.w;
        }
        __syncthreads();
        #pragma unroll
        for (int p = 0; p < 4; ++p) {
            int cl2 = dl8 + 8 * p, dl2 = t & 31;
            Stbf[(size_t)(c0 + cl2) * DIM + d0 + dl2] = f2bf(tile[dl2 * 33 + cl2]);
        }
    }
}

// ---------------- K3: rowloss (2048 blk) | gemm1 64x64 (2048 blk) ------------
#define SEL_CAP 1024
#define GCAP    64

__device__ inline void suffix_select1(unsigned* s_hist, unsigned kk,
                                      unsigned* s_wtot, unsigned* sh_bin,
                                      unsigned* sh_k, int t, int lane, int wid) {
    unsigned h = s_hist[t];
    unsigned v = h;
    #pragma unroll
    for (int off = 1; off < 64; off <<= 1) {
        unsigned o = __shfl_down(v, off);
        if (lane + off < 64) v += o;
    }
    if (lane == 0) s_wtot[wid] = v;
    __syncthreads();
    unsigned above = v - h;
    for (int w2 = wid + 1; w2 < 4; ++w2) above += s_wtot[w2];
    unsigned cum = above + h;
    if (cum >= kk && above < kk) { *sh_bin = (unsigned)t; *sh_k = kk - above; }
    __syncthreads();
}

__global__ __launch_bounds__(256, 8) void k_stage3(const float* __restrict__ sim,
                                                   const int* __restrict__ target,
                                                   const float* __restrict__ rowsig,
                                                   float* __restrict__ loss_part,
                                                   const ushort_t* __restrict__ Pbf,
                                                   const ushort_t* __restrict__ Stbf,
                                                   const float* __restrict__ rnorm,
                                                   ushort_t* __restrict__ logits) {
    __shared__ __align__(16) unsigned char smem[16384];     // 16 KB union
    int bx = blockIdx.x, t = threadIdx.x;
    int lane = t & 63, wid = t >> 6;

    if (bx < 2048) {
        // ================= rowloss (R9 logic, shared mapped into smem) =======
        float*    s_cls  = (float*)smem;                    // 1024 f
        float*    s_bval = (float*)(smem + 4096);           // 1024 f
        ushort_t* s_bcol = (ushort_t*)(smem + 8192);        // 1024 u16
        unsigned* s_bhist= (unsigned*)(smem + 10240);       // 256 u32
        float*    s_gval = (float*)(smem + 11264);          // 64 f
        unsigned* s_wtot = (unsigned*)(smem + 11520);       // 4
        unsigned* shv    = (unsigned*)(smem + 11536);       // cnt, gc, bin, k
        float*    shf    = (float*)(smem + 11552);          // thr
        int*      shi    = (int*)(smem + 11556);            // fb
        float*    red    = (float*)(smem + 11568);          // 4

        int b = bx;
        const float* row = sim + (size_t)b * ALLNUM;
        int tgt = target[b];
        float sig = rowsig[b] * (1.0f / 22.616f);
        float hiT = 1.80f * sig, loT = 1.47f * sig;
        float binscale = 256.0f / (hiT - loT);

        float4 v4[8];
        #pragma unroll
        for (int p = 0; p < 8; ++p) v4[p] = ((const float4*)row)[t + 256 * p];

        if (t == 0) { shv[0] = 0; shv[1] = 0; }
        s_bhist[t] = 0;
        #pragma unroll
        for (int i = 0; i < 4; ++i) s_cls[t + 256 * i] = 0.f;
        __syncthreads();

        float ndef = 0.f;
        #pragma unroll
        for (int p = 0; p < 8; ++p) {
            int f = t + 256 * p;
            int cls = f >> 1;
            const float* pv = (const float*)&v4[p];
            if (cls == tgt) {
                atomicAdd(&s_cls[tgt], pv[0] + pv[1] + pv[2] + pv[3]);
            } else {
                float ds = 0.f;
                #pragma unroll
                for (int e = 0; e < 4; ++e) {
                    float v = pv[e];
                    if (v >= hiT) { ds += v; ndef += 1.f; }
                    else if (v >= loT) {
                        unsigned idx = atomicAdd(&shv[0], 1u);
                        if (idx < SEL_CAP) { s_bval[idx] = v; s_bcol[idx] = (ushort_t)(4 * f + e); }
                        int bin = (int)((v - loT) * binscale);
                        bin = (bin > 255) ? 255 : bin;
                        atomicAdd(&s_bhist[bin], 1u);
                    }
                }
                float o = __shfl_xor(ds, 1);
                float s2 = ds + o;
                if ((t & 1) == 0 && s2 != 0.f) atomicAdd(&s_cls[cls], s2);
            }
        }
        float ndefT = block_reduce(ndef, 0, red, t);
        int bc = (int)shv[0];
        int kq = (TOPK - NPROXY) - (int)ndefT;
        if (t == 0) shi[0] = (kq < 0 || bc < kq || bc > SEL_CAP) ? 1 : 0;
        __syncthreads();

        if (!shi[0]) {
            if (kq > 0) {
                suffix_select1(s_bhist, (unsigned)kq, s_wtot, &shv[2], &shv[3], t, lane, wid);
                int B = (int)shv[2];
                int knew = (int)shv[3];
                for (int j = t; j < bc; j += 256) {
                    float v = s_bval[j];
                    int bin = (int)((v - loT) * binscale);
                    bin = (bin > 255) ? 255 : bin;
                    if (bin == B) {
                        unsigned g = atomicAdd(&shv[1], 1u);
                        if (g < GCAP) s_gval[g] = v;
                    }
                }
                __syncthreads();
                int gc = (int)shv[1];
                if (gc <= GCAP) {
                    if (t < gc) {
                        float vj = s_gval[t];
                        unsigned g = 0, geq = 0;
                        for (int i = 0; i < gc; ++i) {
                            float vi = s_gval[i];
                            g   += (vi > vj) ? 1u : 0u;
                            geq += (vi >= vj) ? 1u : 0u;
                        }
                        if (g < (unsigned)knew && geq >= (unsigned)knew) shf[0] = vj;
                    }
                } else {
                    for (int j = t; j < bc; j += 256) {
                        float vj = s_bval[j];
                        unsigned g = 0, geq = 0;
                        for (int i = 0; i < bc; ++i) {
                            float vi = s_bval[i];
                            g   += (vi > vj) ? 1u : 0u;
                            geq += (vi >= vj) ? 1u : 0u;
                        }
                        if (g < (unsigned)kq && geq >= (unsigned)kq) shf[0] = vj;
                    }
                }
                __syncthreads();
                float thr = shf[0];
                for (int j = t; j < bc; j += 256)
                    if (s_bval[j] >= thr)
                        atomicAdd(&s_cls[s_bcol[j] >> 3], s_bval[j]);
            }
        } else {
            // exact fallback: binary search on ord (never taken for this input)
            __syncthreads();
            #pragma unroll
            for (int i = 0; i < 4; ++i) s_cls[t + 256 * i] = 0.f;
            __syncthreads();
            #pragma unroll
            for (int p = 0; p < 8; ++p) {
                int f = t + 256 * p;
                const float* pv = (const float*)&v4[p];
                if ((f >> 1) == tgt)
                    atomicAdd(&s_cls[tgt], pv[0] + pv[1] + pv[2] + pv[3]);
            }
            unsigned L = 0u, R = 0xFFFFFFFFu;
            for (int it = 0; it < 33 && R - L > 1; ++it) {
                unsigned mid = L + ((R - L) >> 1);
                float c = 0.f;
                #pragma unroll
                for (int p = 0; p < 8; ++p) {
                    int f = t + 256 * p;
                    const float* pv = (const float*)&v4[p];
                    if ((f >> 1) != tgt) {
                        #pragma unroll
                        for (int e = 0; e < 4; ++e)
                            c += (f2ord(pv[e]) >= mid) ? 1.f : 0.f;
                    }
                }
                c = block_reduce(c, 0, red, t);
                if (c >= (float)(TOPK - NPROXY)) L = mid; else R = mid;
                __syncthreads();
            }
            #pragma unroll
            for (int p = 0; p < 8; ++p) {
                int f = t + 256 * p;
                const float* pv = (const float*)&v4[p];
                if ((f >> 1) != tgt) {
                    #pragma unroll
                    for (int e = 0; e < 4; ++e)
                        if (f2ord(pv[e]) >= L)
                            atomicAdd(&s_cls[f >> 1], pv[e]);
                }
            }
        }
        __syncthreads();

        float4 cv = ((const float4*)s_cls)[t];
        float m = -1e30f;
        if (cv.x != 0.0f) m = fmaxf(m, cv.x);
        if (cv.y != 0.0f) m = fmaxf(m, cv.y);
        if (cv.z != 0.0f) m = fmaxf(m, cv.z);
        if (cv.w != 0.0f) m = fmaxf(m, cv.w);
        m = block_reduce(m, 1, red, t);
        float se = 0.f;
        if (cv.x != 0.0f) se += expf(cv.x - m);
        if (cv.y != 0.0f) se += expf(cv.y - m);
        if (cv.z != 0.0f) se += expf(cv.z - m);
        if (cv.w != 0.0f) se += expf(cv.w - m);
        se = block_reduce(se, 0, red, t);
        if (t == 0) {
            float lt = s_cls[tgt];
            float predict_t = expf(lt - m) / (1e-8f * expf(-m) + se);
            loss_part[b] = -logf(predict_t + 1e-20f);
        }
    } else {
        // ================= gemm1: logits = Pbf(8192x512) @ Stbf(1024x512)^T ==
        // 64x64 tiles (16 KB LDS), bf16 out scaled by rnorm[row]
        ushort_t* sA = (ushort_t*)smem;
        ushort_t* sB = (ushort_t*)(smem + 8192);
        int id = bx - 2048;
        int bj = (id & 15) * 64;         // 1024/64 = 16 col-tiles
        int bi = (id >> 4) * 64;         // 8192/64 = 128 row-tiles
        int w = wid;
        int wm = w >> 1, wn = w & 1;     // 2x2 waves of 32x32

        floatx4 acc[2][2];
        #pragma unroll
        for (int tm = 0; tm < 2; ++tm)
            #pragma unroll
            for (int tn = 0; tn < 2; ++tn)
                acc[tm][tn] = (floatx4){0.f, 0.f, 0.f, 0.f};

        for (int k0 = 0; k0 < DIM; k0 += 64) {
            #pragma unroll
            for (int it = 0; it < 2; ++it) {
                int c = (w * 2 + it) * 64 + lane;
                int m = c >> 3, s = c & 7;
                int q = s ^ (m & 7);
                ld_g2l_16(Pbf + ((size_t)(bi + m) << 9) + k0 + q * 8,
                          &sA[((w * 2 + it) * 64) * 8]);
            }
            #pragma unroll
            for (int it = 0; it < 2; ++it) {
                int c = (w * 2 + it) * 64 + lane;
                int m = c >> 3, s = c & 7;
                int q = s ^ (m & 7);
                ld_g2l_16(Stbf + ((size_t)(bj + m) << 9) + k0 + q * 8,
                          &sB[((w * 2 + it) * 64) * 8]);
            }
            asm volatile("s_waitcnt vmcnt(0)" ::: "memory");
            __syncthreads();

            #pragma unroll
            for (int kk = 0; kk < 2; ++kk) {
                bf16x8 af[2], bfr[2];
                int ml = lane & 15, q = lane >> 4;
                #pragma unroll
                for (int tm = 0; tm < 2; ++tm) {
                    int m = wm * 32 + tm * 16 + ml;
                    int s = (kk * 4 + q) ^ (m & 7);
                    af[tm] = *(const bf16x8*)&sA[m * 64 + s * 8];
                }
                #pragma unroll
                for (int tn = 0; tn < 2; ++tn) {
                    int n = wn * 32 + tn * 16 + ml;
                    int s = (kk * 4 + q) ^ (n & 7);
                    bfr[tn] = *(const bf16x8*)&sB[n * 64 + s * 8];
                }
                #pragma unroll
                for (int tm = 0; tm < 2; ++tm)
                    #pragma unroll
                    for (int tn = 0; tn < 2; ++tn)
                        acc[tm][tn] = __builtin_amdgcn_mfma_f32_16x16x32_bf16(
                            af[tm], bfr[tn], acc[tm][tn], 0, 0, 0);
            }
            __syncthreads();
        }

        int ml = lane & 15, qd = lane >> 4;
        #pragma unroll
        for (int tm = 0; tm < 2; ++tm) {
            int rowb = bi + wm * 32 + tm * 16 + qd * 4;
            float4 rnr = *(const float4*)&rnorm[rowb];
            #pragma unroll
            for (int tn = 0; tn < 2; ++tn) {
                int col = bj + wn * 32 + tn * 16 + ml;
                #pragma unroll
                for (int i = 0; i < 4; ++i)
                    logits[(size_t)(rowb + i) * C_CLS + col] =
                        f2bf(acc[tm][tn][i] * ((const float*)&rnr)[i]);
            }
        }
    }
}

// ---------------- K4: reg logsumexp - diag, one wave per row (bf16 in) -------
__global__ __launch_bounds__(256) void k_regloss(const ushort_t* __restrict__ logits,
                                                 float* __restrict__ reg_part) {
    __shared__ float bsum[4];
    int t = threadIdx.x, lane = t & 63, wid = t >> 6;
    int i = blockIdx.x * 4 + wid;
    const ushort_t* row = logits + (size_t)i * C_CLS;
    uint4 c0 = ((const uint4*)row)[lane];
    uint4 c1 = ((const uint4*)(row + 512))[lane];

    float f[16];
    const unsigned* u0 = (const unsigned*)&c0;
    const unsigned* u1 = (const unsigned*)&c1;
    #pragma unroll
    for (int k = 0; k < 4; ++k) {
        f[2 * k]     = __uint_as_float(u0[k] << 16);
        f[2 * k + 1] = __uint_as_float(u0[k] & 0xFFFF0000u);
        f[8 + 2 * k]     = __uint_as_float(u1[k] << 16);
        f[8 + 2 * k + 1] = __uint_as_float(u1[k] & 0xFFFF0000u);
    }

    int cstar = i >> 3;
    int chunk = cstar >> 9, within = cstar & 511;
    float sd = 0.f;
    if (lane == (within >> 3)) sd = f[chunk * 8 + (within & 7)];

    float m = -1e30f;
    #pragma unroll
    for (int k = 0; k < 16; ++k) m = fmaxf(m, f[k]);
    #pragma unroll
    for (int off = 32; off > 0; off >>= 1) m = fmaxf(m, __shfl_xor(m, off));

    float se = 0.f;
    #pragma unroll
    for (int k = 0; k < 16; ++k) se += expf(f[k] - m);
    #pragma unroll
    for (int off = 32; off > 0; off >>= 1) se += __shfl_xor(se, off);
    #pragma unroll
    for (int off = 32; off > 0; off >>= 1) sd += __shfl_xor(sd, off);

    if (lane == 0) bsum[wid] = m + logf(se) - sd;
    __syncthreads();
    if (t == 0)
        reg_part[blockIdx.x] = bsum[0] + bsum[1] + bsum[2] + bsum[3];
}

// ---------------- K5: finalize (reduce 2048+2048 partials) -------------------
__global__ __launch_bounds__(256) void k_final(const float* __restrict__ lp,
                                               const float* __restrict__ rp,
                                               float* __restrict__ out) {
    __shared__ float red[4];
    int t = threadIdx.x;
    float4 a = ((const float4*)lp)[t];
    float4 b = ((const float4*)lp)[t + 256];
    float4 c = ((const float4*)rp)[t];
    float4 d = ((const float4*)rp)[t + 256];
    float ls = a.x + a.y + a.z + a.w + b.x + b.y + b.z + b.w;
    float rs = c.x + c.y + c.z + c.w + d.x + d.y + d.z + d.w;
    ls = block_reduce(ls, 0, red, t);
    rs = block_reduce(rs, 0, red, t);
    if (t == 0) {
        float lc = ls / (float)BATCH;
        float rg = rs / (float)ALLNUM;
        out[0] = lc + LAM * rg;
        out[1] = lc;
    }
}

extern "C" void kernel_launch(void* const* d_in, const int* in_sizes, int n_in,
                              void* d_out, int out_size, void* d_ws, size_t ws_size,
                              hipStream_t stream) {
    const float* input  = (const float*)d_in[0];
    const int*   target = (const int*)d_in[1];
    const float* P      = (const float*)d_in[2];

    float* ws       = (float*)d_ws;
    float* rnorm    = ws + WS_RNORM;
    float* rowsig   = ws + WS_SIG;
    float* loss_part= ws + WS_LP;
    float* reg_part = ws + WS_RP;
    ushort_t* Abf   = (ushort_t*)(ws + WS_ABF);
    ushort_t* Pbf   = (ushort_t*)(ws + WS_PBF);
    ushort_t* Stbf  = (ushort_t*)(ws + WS_STBF);
    ushort_t* logits= (ushort_t*)(ws + WS_LOG);
    float* sim      = ws + WS_SIM;
    float* out      = (float*)d_out;

    hipLaunchKernelGGL(k_prep1, dim3(256 + 1024 + 4096), dim3(256), 0, stream,
                       P, input, rnorm, rowsig, Abf, Pbf);
    hipLaunchKernelGGL(k_stage2, dim3(1024 + 512), dim3(256), 0, stream,
                       Abf, Pbf, P, rnorm, sim, Stbf);
    hipLaunchKernelGGL(k_stage3, dim3(2048 + 2048), dim3(256), 0, stream,
                       sim, target, rowsig, loss_part, Pbf, Stbf, rnorm, logits);
    hipLaunchKernelGGL(k_regloss, dim3(ALLNUM / 4), dim3(256), 0, stream,
                       logits, reg_part);
    hipLaunchKernelGGL(k_final, dim3(1), dim3(256), 0, stream,
                       loss_part, reg_part, out);
}

// Round 12
// 153.754 us; speedup vs baseline: 1.3113x; 1.3113x over previous
//
#include <hip/hip_runtime.h>
#include <hip/hip_bf16.h>
#include <math.h>

#define C_CLS   1024
#define NPROXY  8
#define ALLNUM  8192
#define DIM     512
#define TOPK    410
#define LAM     0.3f
#define BATCH   2048

typedef __bf16 bf16x8 __attribute__((ext_vector_type(8)));
typedef float floatx4 __attribute__((ext_vector_type(4)));
typedef unsigned short ushort_t;

// ws layout (float offsets)
#define WS_RNORM 0                      // 8192
#define WS_SIG   8192                   // 2048
#define WS_LP    10240                  // 2048
#define WS_RP    12288                  // 2048
#define WS_ABF   14336                  // 2048*512 bf16 = 524288 float-slots
#define WS_PBF   538624                 // 8192*512 bf16 = 2097152
#define WS_STBF  2635776                // 1024*512 bf16 = 262144
#define WS_LOG   2897920                // 8192*1024 bf16 = 4194304 (NOT aliased w/ sim!)
#define WS_SIM   7092224                // 2048*8192 fp32 = 16777216

// ---------------- helpers ----------------------------------------------------
__device__ inline float block_reduce(float v, int is_max, float* red, int t) {
    #pragma unroll
    for (int o = 32; o > 0; o >>= 1) {
        float w = __shfl_down(v, o);
        v = is_max ? fmaxf(v, w) : (v + w);
    }
    __syncthreads();
    if ((t & 63) == 0) red[t >> 6] = v;
    __syncthreads();
    return is_max ? fmaxf(fmaxf(red[0], red[1]), fmaxf(red[2], red[3]))
                  : (red[0] + red[1] + red[2] + red[3]);
}

__device__ inline ushort_t f2bf(float f) {   // RNE float->bf16
    unsigned u = __float_as_uint(f);
    return (ushort_t)((u + 0x7FFFu + ((u >> 16) & 1u)) >> 16);
}

__device__ inline void ld_g2l_16(const void* g, void* l) {
    __builtin_amdgcn_global_load_lds(
        (const __attribute__((address_space(1))) unsigned int*)g,
        (__attribute__((address_space(3))) unsigned int*)l,
        16, 0, 0);
}

__device__ inline unsigned f2ord(float f) {  // monotone float->uint
    unsigned u = __float_as_uint(f);
    return (u & 0x80000000u) ? ~u : (u | 0x80000000u);
}

// ---------------- K1: colnorm(256 blk) | convA+rowsig(1024) | tconvP(4096) ---
__global__ __launch_bounds__(256) void k_prep1(const float* __restrict__ P,
                                               const float* __restrict__ input,
                                               float* __restrict__ rnorm,
                                               float* __restrict__ rowsig,
                                               ushort_t* __restrict__ Abf,
                                               ushort_t* __restrict__ Pbf) {
    __shared__ float tile[32][33];
    float* cred = &tile[0][0];
    int bx = blockIdx.x, t = threadIdx.x;
    if (bx < 256) {
        // colnorm: 32 cols/block, 8 d-groups of 64
        int tc = t & 31, g = t >> 5;
        int c = bx * 32 + tc;
        const float* pc = P + (size_t)(g * 64) * ALLNUM + c;
        float s = 0.f;
        #pragma unroll 8
        for (int d = 0; d < 64; ++d) {
            float v = pc[(size_t)d * ALLNUM];
            s += v * v;
        }
        cred[g * 32 + tc] = s;
        __syncthreads();
        if (g == 0) {
            float tot = 0.f;
            #pragma unroll
            for (int k = 0; k < 8; ++k) tot += cred[k * 32 + tc];
            rnorm[c] = 1.0f / fmaxf(sqrtf(tot), 1e-12f);
        }
    } else if (bx < 256 + 1024) {
        // convA: input fp32 -> bf16 + row norms (block = exactly 2 rows)
        int a = bx - 256;
        int idx = a * 256 + t;
        float4 v = ((const float4*)input)[idx];
        ushort4 o;
        o.x = f2bf(v.x); o.y = f2bf(v.y); o.z = f2bf(v.z); o.w = f2bf(v.w);
        ((ushort4*)Abf)[idx] = o;
        float sq = v.x * v.x + v.y * v.y + v.z * v.z + v.w * v.w;
        #pragma unroll
        for (int off = 32; off > 0; off >>= 1) sq += __shfl_down(sq, off);
        int lane = t & 63, w = t >> 6;
        if (lane == 0) cred[w] = sq;
        __syncthreads();
        if (t == 0) {
            rowsig[2 * a]     = sqrtf(cred[0] + cred[1]);
            rowsig[2 * a + 1] = sqrtf(cred[2] + cred[3]);
        }
    } else {
        // tconv: P [512][8192] fp32 -> Pbf [8192][512] bf16
        int id = bx - 1280;
        int c0 = (id & 255) * 32, r0 = (id >> 8) * 32;
        int tc = t & 31, tr = t >> 5;
        #pragma unroll
        for (int p = 0; p < 4; ++p)
            tile[tr + p * 8][tc] = P[(size_t)(r0 + tr + p * 8) * ALLNUM + c0 + tc];
        __syncthreads();
        #pragma unroll
        for (int p = 0; p < 4; ++p) {
            int oc = tr + p * 8;
            Pbf[(size_t)(c0 + oc) * DIM + r0 + tc] = f2bf(tile[tc][oc]);
        }
    }
}

// ---------------- K2: gemm0 (sim f32, 1024 blk) | buildSt (512 blk) ----------
__global__ __launch_bounds__(256) void k_stage2(const ushort_t* __restrict__ A,
                                                const ushort_t* __restrict__ B,
                                                const float* __restrict__ P,
                                                const float* __restrict__ rnorm,
                                                float* __restrict__ sim,
                                                ushort_t* __restrict__ Stbf) {
    __shared__ __align__(16) ushort_t smem[2 * 128 * 64];   // 32 KB
    int bx = blockIdx.x, t = threadIdx.x;

    if (bx < 1024) {
        // ---- gemm0: sim = A(2048x512) @ B(8192x512)^T, *rnorm[col], f32 out
        ushort_t* sA = smem;
        ushort_t* sB = smem + 128 * 64;
        int w = t >> 6, lane = t & 63;
        int wm = w >> 1, wn = w & 1;
        int bj = (bx & 63) * 128, bi = (bx >> 6) * 128;

        floatx4 acc[4][4];
        #pragma unroll
        for (int tm = 0; tm < 4; ++tm)
            #pragma unroll
            for (int tn = 0; tn < 4; ++tn)
                acc[tm][tn] = (floatx4){0.f, 0.f, 0.f, 0.f};

        for (int k0 = 0; k0 < DIM; k0 += 64) {
            #pragma unroll
            for (int it = 0; it < 4; ++it) {
                int c = w * 256 + it * 64 + lane;
                int m = c >> 3, s = c & 7;
                int q = s ^ (m & 7);
                ld_g2l_16(A + ((size_t)(bi + m) << 9) + k0 + q * 8,
                          &sA[(w * 256 + it * 64) * 8]);
            }
            #pragma unroll
            for (int it = 0; it < 4; ++it) {
                int c = w * 256 + it * 64 + lane;
                int m = c >> 3, s = c & 7;
                int q = s ^ (m & 7);
                ld_g2l_16(B + ((size_t)(bj + m) << 9) + k0 + q * 8,
                          &sB[(w * 256 + it * 64) * 8]);
            }
            asm volatile("s_waitcnt vmcnt(0)" ::: "memory");
            __syncthreads();

            #pragma unroll
            for (int kk = 0; kk < 2; ++kk) {
                bf16x8 af[4], bfr[4];
                int ml = lane & 15, q = lane >> 4;
                #pragma unroll
                for (int tm = 0; tm < 4; ++tm) {
                    int m = wm * 64 + tm * 16 + ml;
                    int s = (kk * 4 + q) ^ (m & 7);
                    af[tm] = *(const bf16x8*)&sA[m * 64 + s * 8];
                }
                #pragma unroll
                for (int tn = 0; tn < 4; ++tn) {
                    int n = wn * 64 + tn * 16 + ml;
                    int s = (kk * 4 + q) ^ (n & 7);
                    bfr[tn] = *(const bf16x8*)&sB[n * 64 + s * 8];
                }
                #pragma unroll
                for (int tm = 0; tm < 4; ++tm)
                    #pragma unroll
                    for (int tn = 0; tn < 4; ++tn)
                        acc[tm][tn] = __builtin_amdgcn_mfma_f32_16x16x32_bf16(
                            af[tm], bfr[tn], acc[tm][tn], 0, 0, 0);
            }
            __syncthreads();
        }

        int ml = lane & 15, qd = lane >> 4;
        #pragma unroll
        for (int tm = 0; tm < 4; ++tm) {
            int rowb = bi + wm * 64 + tm * 16 + qd * 4;
            #pragma unroll
            for (int tn = 0; tn < 4; ++tn) {
                int col = bj + wn * 64 + tn * 16 + ml;
                float sc = rnorm[col];
                #pragma unroll
                for (int i = 0; i < 4; ++i)
                    sim[(size_t)(rowb + i) * ALLNUM + col] = acc[tm][tn][i] * sc;
            }
        }
    } else {
        // ---- buildSt: St[c][d] = sum_n P[d][8c+n]*rnorm[8c+n], bf16 out
        // 512 blocks: 32 c-tiles x 16 d-tiles (d0 < 512!)
        float* tile = (float*)smem;          // [32][33]
        int id = bx - 1024;                  // 0..511
        int c0 = (id & 31) * 32, d0 = (id >> 5) * 32;
        int cl = t & 31, dl8 = t >> 5;
        #pragma unroll
        for (int p = 0; p < 4; ++p) {
            int d = d0 + dl8 + 8 * p;
            int c = c0 + cl;
            const float* pp = P + (size_t)d * ALLNUM + c * NPROXY;
            const float* rn = rnorm + c * NPROXY;
            float4 a = *(const float4*)pp;
            float4 b = *(const float4*)(pp + 4);
            float4 ra = *(const float4*)rn;
            float4 rb = *(const float4*)(rn + 4);
            tile[(dl8 + 8 * p) * 33 + cl] =
                a.x * ra.x + a.y * ra.y + a.z * ra.z + a.w * ra.w +
                b.x * rb.x + b.y * rb.y + b.z * rb.z + b.w * rb.w;
        }
        __syncthreads();
        #pragma unroll
        for (int p = 0; p < 4; ++p) {
            int cl2 = dl8 + 8 * p, dl2 = t & 31;
            Stbf[(size_t)(c0 + cl2) * DIM + d0 + dl2] = f2bf(tile[dl2 * 33 + cl2]);
        }
    }
}

// ---------------- K3: rowloss (2048 blk) | gemm1 64x64 (2048 blk) ------------
#define SEL_CAP 1024
#define GCAP    64

__device__ inline void suffix_select1(unsigned* s_hist, unsigned kk,
                                      unsigned* s_wtot, unsigned* sh_bin,
                                      unsigned* sh_k, int t, int lane, int wid) {
    unsigned h = s_hist[t];
    unsigned v = h;
    #pragma unroll
    for (int off = 1; off < 64; off <<= 1) {
        unsigned o = __shfl_down(v, off);
        if (lane + off < 64) v += o;
    }
    if (lane == 0) s_wtot[wid] = v;
    __syncthreads();
    unsigned above = v - h;
    for (int w2 = wid + 1; w2 < 4; ++w2) above += s_wtot[w2];
    unsigned cum = above + h;
    if (cum >= kk && above < kk) { *sh_bin = (unsigned)t; *sh_k = kk - above; }
    __syncthreads();
}

__global__ __launch_bounds__(256) void k_stage3(const float* __restrict__ sim,
                                                const int* __restrict__ target,
                                                const float* __restrict__ rowsig,
                                                float* __restrict__ loss_part,
                                                const ushort_t* __restrict__ Pbf,
                                                const ushort_t* __restrict__ Stbf,
                                                const float* __restrict__ rnorm,
                                                ushort_t* __restrict__ logits) {
    __shared__ __align__(16) unsigned char smem[16384];     // 16 KB union
    int bx = blockIdx.x, t = threadIdx.x;
    int lane = t & 63, wid = t >> 6;

    if (bx < 2048) {
        // ================= rowloss (R9 logic, shared mapped into smem) =======
        float*    s_cls  = (float*)smem;                    // 1024 f
        float*    s_bval = (float*)(smem + 4096);           // 1024 f
        ushort_t* s_bcol = (ushort_t*)(smem + 8192);        // 1024 u16
        unsigned* s_bhist= (unsigned*)(smem + 10240);       // 256 u32
        float*    s_gval = (float*)(smem + 11264);          // 64 f
        unsigned* s_wtot = (unsigned*)(smem + 11520);       // 4
        unsigned* shv    = (unsigned*)(smem + 11536);       // cnt, gc, bin, k
        float*    shf    = (float*)(smem + 11552);          // thr
        int*      shi    = (int*)(smem + 11556);            // fb
        float*    red    = (float*)(smem + 11568);          // 4

        int b = bx;
        const float* row = sim + (size_t)b * ALLNUM;
        int tgt = target[b];
        float sig = rowsig[b] * (1.0f / 22.616f);
        float hiT = 1.80f * sig, loT = 1.47f * sig;
        float binscale = 256.0f / (hiT - loT);

        float4 v4[8];
        #pragma unroll
        for (int p = 0; p < 8; ++p) v4[p] = ((const float4*)row)[t + 256 * p];

        if (t == 0) { shv[0] = 0; shv[1] = 0; }
        s_bhist[t] = 0;
        #pragma unroll
        for (int i = 0; i < 4; ++i) s_cls[t + 256 * i] = 0.f;
        __syncthreads();

        float ndef = 0.f;
        #pragma unroll
        for (int p = 0; p < 8; ++p) {
            int f = t + 256 * p;
            int cls = f >> 1;
            const float* pv = (const float*)&v4[p];
            if (cls == tgt) {
                atomicAdd(&s_cls[tgt], pv[0] + pv[1] + pv[2] + pv[3]);
            } else {
                float ds = 0.f;
                #pragma unroll
                for (int e = 0; e < 4; ++e) {
                    float v = pv[e];
                    if (v >= hiT) { ds += v; ndef += 1.f; }
                    else if (v >= loT) {
                        unsigned idx = atomicAdd(&shv[0], 1u);
                        if (idx < SEL_CAP) { s_bval[idx] = v; s_bcol[idx] = (ushort_t)(4 * f + e); }
                        int bin = (int)((v - loT) * binscale);
                        bin = (bin > 255) ? 255 : bin;
                        atomicAdd(&s_bhist[bin], 1u);
                    }
                }
                float o = __shfl_xor(ds, 1);
                float s2 = ds + o;
                if ((t & 1) == 0 && s2 != 0.f) atomicAdd(&s_cls[cls], s2);
            }
        }
        float ndefT = block_reduce(ndef, 0, red, t);
        int bc = (int)shv[0];
        int kq = (TOPK - NPROXY) - (int)ndefT;
        if (t == 0) shi[0] = (kq < 0 || bc < kq || bc > SEL_CAP) ? 1 : 0;
        __syncthreads();

        if (!shi[0]) {
            if (kq > 0) {
                suffix_select1(s_bhist, (unsigned)kq, s_wtot, &shv[2], &shv[3], t, lane, wid);
                int B = (int)shv[2];
                int knew = (int)shv[3];
                for (int j = t; j < bc; j += 256) {
                    float v = s_bval[j];
                    int bin = (int)((v - loT) * binscale);
                    bin = (bin > 255) ? 255 : bin;
                    if (bin == B) {
                        unsigned g = atomicAdd(&shv[1], 1u);
                        if (g < GCAP) s_gval[g] = v;
                    }
                }
                __syncthreads();
                int gc = (int)shv[1];
                if (gc <= GCAP) {
                    if (t < gc) {
                        float vj = s_gval[t];
                        unsigned g = 0, geq = 0;
                        for (int i = 0; i < gc; ++i) {
                            float vi = s_gval[i];
                            g   += (vi > vj) ? 1u : 0u;
                            geq += (vi >= vj) ? 1u : 0u;
                        }
                        if (g < (unsigned)knew && geq >= (unsigned)knew) shf[0] = vj;
                    }
                } else {
                    for (int j = t; j < bc; j += 256) {
                        float vj = s_bval[j];
                        unsigned g = 0, geq = 0;
                        for (int i = 0; i < bc; ++i) {
                            float vi = s_bval[i];
                            g   += (vi > vj) ? 1u : 0u;
                            geq += (vi >= vj) ? 1u : 0u;
                        }
                        if (g < (unsigned)kq && geq >= (unsigned)kq) shf[0] = vj;
                    }
                }
                __syncthreads();
                float thr = shf[0];
                for (int j = t; j < bc; j += 256)
                    if (s_bval[j] >= thr)
                        atomicAdd(&s_cls[s_bcol[j] >> 3], s_bval[j]);
            }
        } else {
            // exact fallback: binary search on ord (never taken for this input)
            __syncthreads();
            #pragma unroll
            for (int i = 0; i < 4; ++i) s_cls[t + 256 * i] = 0.f;
            __syncthreads();
            #pragma unroll
            for (int p = 0; p < 8; ++p) {
                int f = t + 256 * p;
                const float* pv = (const float*)&v4[p];
                if ((f >> 1) == tgt)
                    atomicAdd(&s_cls[tgt], pv[0] + pv[1] + pv[2] + pv[3]);
            }
            unsigned L = 0u, R = 0xFFFFFFFFu;
            for (int it = 0; it < 33 && R - L > 1; ++it) {
                unsigned mid = L + ((R - L) >> 1);
                float c = 0.f;
                #pragma unroll
                for (int p = 0; p < 8; ++p) {
                    int f = t + 256 * p;
                    const float* pv = (const float*)&v4[p];
                    if ((f >> 1) != tgt) {
                        #pragma unroll
                        for (int e = 0; e < 4; ++e)
                            c += (f2ord(pv[e]) >= mid) ? 1.f : 0.f;
                    }
                }
                c = block_reduce(c, 0, red, t);
                if (c >= (float)(TOPK - NPROXY)) L = mid; else R = mid;
                __syncthreads();
            }
            #pragma unroll
            for (int p = 0; p < 8; ++p) {
                int f = t + 256 * p;
                const float* pv = (const float*)&v4[p];
                if ((f >> 1) != tgt) {
                    #pragma unroll
                    for (int e = 0; e < 4; ++e)
                        if (f2ord(pv[e]) >= L)
                            atomicAdd(&s_cls[f >> 1], pv[e]);
                }
            }
        }
        __syncthreads();

        float4 cv = ((const float4*)s_cls)[t];
        float m = -1e30f;
        if (cv.x != 0.0f) m = fmaxf(m, cv.x);
        if (cv.y != 0.0f) m = fmaxf(m, cv.y);
        if (cv.z != 0.0f) m = fmaxf(m, cv.z);
        if (cv.w != 0.0f) m = fmaxf(m, cv.w);
        m = block_reduce(m, 1, red, t);
        float se = 0.f;
        if (cv.x != 0.0f) se += expf(cv.x - m);
        if (cv.y != 0.0f) se += expf(cv.y - m);
        if (cv.z != 0.0f) se += expf(cv.z - m);
        if (cv.w != 0.0f) se += expf(cv.w - m);
        se = block_reduce(se, 0, red, t);
        if (t == 0) {
            float lt = s_cls[tgt];
            float predict_t = expf(lt - m) / (1e-8f * expf(-m) + se);
            loss_part[b] = -logf(predict_t + 1e-20f);
        }
    } else {
        // ================= gemm1: logits = Pbf(8192x512) @ Stbf(1024x512)^T ==
        // 64x64 tiles (16 KB LDS), bf16 out scaled by rnorm[row]
        ushort_t* sA = (ushort_t*)smem;
        ushort_t* sB = (ushort_t*)(smem + 8192);
        int id = bx - 2048;
        int bj = (id & 15) * 64;         // 1024/64 = 16 col-tiles
        int bi = (id >> 4) * 64;         // 8192/64 = 128 row-tiles
        int w = wid;
        int wm = w >> 1, wn = w & 1;     // 2x2 waves of 32x32

        floatx4 acc[2][2];
        #pragma unroll
        for (int tm = 0; tm < 2; ++tm)
            #pragma unroll
            for (int tn = 0; tn < 2; ++tn)
                acc[tm][tn] = (floatx4){0.f, 0.f, 0.f, 0.f};

        for (int k0 = 0; k0 < DIM; k0 += 64) {
            #pragma unroll
            for (int it = 0; it < 2; ++it) {
                int c = (w * 2 + it) * 64 + lane;
                int m = c >> 3, s = c & 7;
                int q = s ^ (m & 7);
                ld_g2l_16(Pbf + ((size_t)(bi + m) << 9) + k0 + q * 8,
                          &sA[((w * 2 + it) * 64) * 8]);
            }
            #pragma unroll
            for (int it = 0; it < 2; ++it) {
                int c = (w * 2 + it) * 64 + lane;
                int m = c >> 3, s = c & 7;
                int q = s ^ (m & 7);
                ld_g2l_16(Stbf + ((size_t)(bj + m) << 9) + k0 + q * 8,
                          &sB[((w * 2 + it) * 64) * 8]);
            }
            asm volatile("s_waitcnt vmcnt(0)" ::: "memory");
            __syncthreads();

            #pragma unroll
            for (int kk = 0; kk < 2; ++kk) {
                bf16x8 af[2], bfr[2];
                int ml = lane & 15, q = lane >> 4;
                #pragma unroll
                for (int tm = 0; tm < 2; ++tm) {
                    int m = wm * 32 + tm * 16 + ml;
                    int s = (kk * 4 + q) ^ (m & 7);
                    af[tm] = *(const bf16x8*)&sA[m * 64 + s * 8];
                }
                #pragma unroll
                for (int tn = 0; tn < 2; ++tn) {
                    int n = wn * 32 + tn * 16 + ml;
                    int s = (kk * 4 + q) ^ (n & 7);
                    bfr[tn] = *(const bf16x8*)&sB[n * 64 + s * 8];
                }
                #pragma unroll
                for (int tm = 0; tm < 2; ++tm)
                    #pragma unroll
                    for (int tn = 0; tn < 2; ++tn)
                        acc[tm][tn] = __builtin_amdgcn_mfma_f32_16x16x32_bf16(
                            af[tm], bfr[tn], acc[tm][tn], 0, 0, 0);
            }
            __syncthreads();
        }

        int ml = lane & 15, qd = lane >> 4;
        #pragma unroll
        for (int tm = 0; tm < 2; ++tm) {
            int rowb = bi + wm * 32 + tm * 16 + qd * 4;
            float4 rnr = *(const float4*)&rnorm[rowb];
            #pragma unroll
            for (int tn = 0; tn < 2; ++tn) {
                int col = bj + wn * 32 + tn * 16 + ml;
                #pragma unroll
                for (int i = 0; i < 4; ++i)
                    logits[(size_t)(rowb + i) * C_CLS + col] =
                        f2bf(acc[tm][tn][i] * ((const float*)&rnr)[i]);
            }
        }
    }
}

// ---------------- K4: reg logsumexp - diag, one wave per row (bf16 in) -------
__global__ __launch_bounds__(256) void k_regloss(const ushort_t* __restrict__ logits,
                                                 float* __restrict__ reg_part) {
    __shared__ float bsum[4];
    int t = threadIdx.x, lane = t & 63, wid = t >> 6;
    int i = blockIdx.x * 4 + wid;
    const ushort_t* row = logits + (size_t)i * C_CLS;
    uint4 c0 = ((const uint4*)row)[lane];
    uint4 c1 = ((const uint4*)(row + 512))[lane];

    float f[16];
    const unsigned* u0 = (const unsigned*)&c0;
    const unsigned* u1 = (const unsigned*)&c1;
    #pragma unroll
    for (int k = 0; k < 4; ++k) {
        f[2 * k]     = __uint_as_float(u0[k] << 16);
        f[2 * k + 1] = __uint_as_float(u0[k] & 0xFFFF0000u);
        f[8 + 2 * k]     = __uint_as_float(u1[k] << 16);
        f[8 + 2 * k + 1] = __uint_as_float(u1[k] & 0xFFFF0000u);
    }

    int cstar = i >> 3;
    int chunk = cstar >> 9, within = cstar & 511;
    float sd = 0.f;
    if (lane == (within >> 3)) sd = f[chunk * 8 + (within & 7)];

    float m = -1e30f;
    #pragma unroll
    for (int k = 0; k < 16; ++k) m = fmaxf(m, f[k]);
    #pragma unroll
    for (int off = 32; off > 0; off >>= 1) m = fmaxf(m, __shfl_xor(m, off));

    float se = 0.f;
    #pragma unroll
    for (int k = 0; k < 16; ++k) se += expf(f[k] - m);
    #pragma unroll
    for (int off = 32; off > 0; off >>= 1) se += __shfl_xor(se, off);
    #pragma unroll
    for (int off = 32; off > 0; off >>= 1) sd += __shfl_xor(sd, off);

    if (lane == 0) bsum[wid] = m + logf(se) - sd;
    __syncthreads();
    if (t == 0)
        reg_part[blockIdx.x] = bsum[0] + bsum[1] + bsum[2] + bsum[3];
}

// ---------------- K5: finalize (reduce 2048+2048 partials) -------------------
__global__ __launch_bounds__(256) void k_final(const float* __restrict__ lp,
                                               const float* __restrict__ rp,
                                               float* __restrict__ out) {
    __shared__ float red[4];
    int t = threadIdx.x;
    float4 a = ((const float4*)lp)[t];
    float4 b = ((const float4*)lp)[t + 256];
    float4 c = ((const float4*)rp)[t];
    float4 d = ((const float4*)rp)[t + 256];
    float ls = a.x + a.y + a.z + a.w + b.x + b.y + b.z + b.w;
    float rs = c.x + c.y + c.z + c.w + d.x + d.y + d.z + d.w;
    ls = block_reduce(ls, 0, red, t);
    rs = block_reduce(rs, 0, red, t);
    if (t == 0) {
        float lc = ls / (float)BATCH;
        float rg = rs / (float)ALLNUM;
        out[0] = lc + LAM * rg;
        out[1] = lc;
    }
}

extern "C" void kernel_launch(void* const* d_in, const int* in_sizes, int n_in,
                              void* d_out, int out_size, void* d_ws, size_t ws_size,
                              hipStream_t stream) {
    const float* input  = (const float*)d_in[0];
    const int*   target = (const int*)d_in[1];
    const float* P      = (const float*)d_in[2];

    float* ws       = (float*)d_ws;
    float* rnorm    = ws + WS_RNORM;
    float* rowsig   = ws + WS_SIG;
    float* loss_part= ws + WS_LP;
    float* reg_part = ws + WS_RP;
    ushort_t* Abf   = (ushort_t*)(ws + WS_ABF);
    ushort_t* Pbf   = (ushort_t*)(ws + WS_PBF);
    ushort_t* Stbf  = (ushort_t*)(ws + WS_STBF);
    ushort_t* logits= (ushort_t*)(ws + WS_LOG);
    float* sim      = ws + WS_SIM;
    float* out      = (float*)d_out;

    hipLaunchKernelGGL(k_prep1, dim3(256 + 1024 + 4096), dim3(256), 0, stream,
                       P, input, rnorm, rowsig, Abf, Pbf);
    hipLaunchKernelGGL(k_stage2, dim3(1024 + 512), dim3(256), 0, stream,
                       Abf, Pbf, P, rnorm, sim, Stbf);
    hipLaunchKernelGGL(k_stage3, dim3(2048 + 2048), dim3(256), 0, stream,
                       sim, target, rowsig, loss_part, Pbf, Stbf, rnorm, logits);
    hipLaunchKernelGGL(k_regloss, dim3(ALLNUM / 4), dim3(256), 0, stream,
                       logits, reg_part);
    hipLaunchKernelGGL(k_final, dim3(1), dim3(256), 0, stream,
                       loss_part, reg_part, out);
}